// Round 10
// baseline (320.097 us; speedup 1.0000x reference)
//
#include <hip/hip_runtime.h>
#include <math.h>

#define B_ 2
#define T_ 1024
#define C_ 768
#define NH 12
#define NBR 4
#define DH_ 64
#define HT 48
#define MROWS (B_*T_)   // 2048

#define SCALE_W 1.8137993642342178f   // pi/sqrt(3)
#define ATTNSCALE_ 0.125f             // 64^-0.5

// ---------------- workspace layout (float offsets, audited) ----------------
#define OFF_B1    0                          // fp32[1024*32]
#define OFF_B2    (OFF_B1 + 32768)           // 32768   fp32[1024*32]
#define OFF_QKVB  (OFF_B2 + 32768)           // 65536   fp32[4608]  (Ebq|bk|bv)
#define OFF_BSUM  (OFF_QKVB + 4608)          // 70144   fp32[768]
#define OFF_WQKV  (OFF_BSUM + 768)           // 70912   ushort[4608*768] -> 1769472 fl
#define OFF_XB    (OFF_WQKV + 1769472)       // 1840384 ushort[2048*768] -> 786432 fl
#define OFF_WOT   (OFF_XB + 786432)          // 2626816 ushort[768*3072] -> 1179648 fl
#define OFF_QF    (OFF_WOT + 1179648)        // 3806464 fp32[2048*3072] = 6291456 fl
#define OFF_KF    (OFF_QF + 6291456)         // 10097920 fp32[2048*768] = 1572864 fl
#define OFF_VF    (OFF_KF + 1572864)         // 11670784 fp32[2048*768]
// bf16 Q aliases dead fp32 KF+VF (needs 3145728 fl, KF+VF = 3145728 exactly)
#define OFF_QB    OFF_KF
#define OFF_KB    (OFF_VF + 1572864)         // 13243648 ushort[2*12*1024*64] -> 786432 fl
#define OFF_VB    (OFF_KB + 786432)          // 14030080 -> 786432 fl  (V^T head-major)
#define OFF_RKS   (OFF_VB + 786432)          // 14816512 fp32[24576]
// bf16 ctx aliases dead fp32 QF (needs 3145728 fl of 6291456)
#define OFF_CTXB  OFF_QF
// end = 14841088 floats = 59.4 MB

typedef __attribute__((ext_vector_type(8))) short short8t;
typedef __attribute__((ext_vector_type(4))) float f32x4;

__device__ inline ushort f2bf(float f) {
    union { float f; unsigned u; } v; v.f = f;
    unsigned r = (v.u + 0x7FFFu + ((v.u >> 16) & 1u)) >> 16;
    return (ushort)r;
}

typedef __attribute__((address_space(3))) void lds_vt;
typedef const __attribute__((address_space(1))) void gbl_vt;
static __device__ __forceinline__ void gload16(const void* g, void* l) {
    __builtin_amdgcn_global_load_lds((gbl_vt*)g, (lds_vt*)l, 16, 0, 0);
}

// ---------------------------------------------------------------------------
__global__ void cheb_kernel(float* __restrict__ ws) {
    int t = blockIdx.x * 256 + threadIdx.x;
    if (t >= T_) return;
    float* b1 = ws + OFF_B1 + t * 32;
    float* b2 = ws + OFF_B2 + t * 32;
    float x = 2.0f * (float)t / 1023.0f - 1.0f;
    float Tp = 1.0f, Tc = x;
    for (int j = 0; j < 32; j++) {
        float r1 = Tc;
        float r2 = 2.0f * x * Tc - Tp;
        float nr = sqrtf(r1 * r1 + r2 * r2 + 1e-8f);
        b1[j] = r1 / nr;
        b2[j] = r2 / nr;
        Tp = r2;
        Tc = 2.0f * x * r2 - r1;
    }
}

// ---------------------------------------------------------------------------
// Fold M_h into Wq -> bf16 rows [0,3072) of WQKV; Ebq -> QKVB[0..3072)
__global__ __launch_bounds__(256) void prep_wq(
    const float* __restrict__ Aw, const float* __restrict__ idb,
    const float* __restrict__ Wq, const float* __restrict__ bq,
    float* __restrict__ ws) {
    __shared__ float Ms[64][64];
    int h = blockIdx.x;
    int tid = threadIdx.x;
    for (int i = tid; i < 4096; i += 256) {
        int d = i >> 6, e = i & 63;
        float v = Aw[d * 64 + e] - Aw[e * 64 + d];
        if (d == e) v += 1.0f + idb[h * 64 + d];
        Ms[d][e] = v;
    }
    __syncthreads();
    int c = blockIdx.y * 256 + tid;
    float wq[64];
#pragma unroll
    for (int d = 0; d < 64; d++) wq[d] = Wq[(size_t)(h * 64 + d) * 768 + c];
    ushort* EWqb = (ushort*)(ws + OFF_WQKV);
    for (int e = 0; e < 64; e++) {
        float acc = 0.f;
#pragma unroll
        for (int d = 0; d < 64; d++) acc += Ms[d][e] * wq[d];
        EWqb[(size_t)(h * 64 + e) * 768 + c] = f2bf(acc);
    }
    if (blockIdx.y == 0 && tid < 64) {
        int e = tid;
        float acc = 0.f;
        for (int d = 0; d < 64; d++) acc += Ms[d][e] * bq[h * 64 + d];
        ws[OFF_QKVB + h * 64 + e] = acc;
    }
}

// ---------------------------------------------------------------------------
__global__ void conv_bf16(const float* __restrict__ src, ushort* __restrict__ dst) {
    int i = (blockIdx.x * 256 + threadIdx.x) * 4;
    float4 v = *(const float4*)(src + i);
    ushort4 o;
    o.x = f2bf(v.x); o.y = f2bf(v.y); o.z = f2bf(v.z); o.w = f2bf(v.w);
    *(ushort4*)(dst + i) = o;
}

// ---------------------------------------------------------------------------
// WoT[c][nb*768+k] = bf16(Wo[nb][k][c])   grid (12,12,4)
__global__ __launch_bounds__(256) void woT_kernel(const float* __restrict__ Wo,
                                                  ushort* __restrict__ WoT) {
    __shared__ float tile[64][65];
    int nb = blockIdx.z;
    int k0 = blockIdx.x * 64, c0 = blockIdx.y * 64;
    int tx = threadIdx.x & 63, ty = threadIdx.x >> 6;
#pragma unroll
    for (int p = 0; p < 16; p++) {
        int ky = p * 4 + ty;
        tile[ky][tx] = Wo[((size_t)nb * 768 + k0 + ky) * 768 + c0 + tx];
    }
    __syncthreads();
#pragma unroll
    for (int p = 0; p < 16; p++) {
        int cy = p * 4 + ty;
        WoT[(size_t)(c0 + cy) * 3072 + nb * 768 + k0 + tx] = f2bf(tile[tx][cy]);
    }
}

// bsum + pack bk,bv into QKVB tail
__global__ void bias_prep(const float* __restrict__ bo, const float* __restrict__ bk,
                          const float* __restrict__ bv, float* __restrict__ ws) {
    int n = blockIdx.x * 256 + threadIdx.x;
    if (n < 768) {
        ws[OFF_BSUM + n] = 0.25f * (bo[n] + bo[768 + n] + bo[1536 + n] + bo[2304 + n]);
        ws[OFF_QKVB + 3072 + n] = bk[n];
        ws[OFF_QKVB + 3840 + n] = bv[n];
    }
}

// Y pre-init with branch-mean bias (gemm_fin accumulates atomically on top)
__global__ void y_init(const float* __restrict__ bsum, float* __restrict__ Y) {
    int idx = (blockIdx.x * 256 + threadIdx.x) * 4;
    int n = idx - (idx / 768) * 768;
    float4 o = { bsum[n], bsum[n + 1], bsum[n + 2], bsum[n + 3] };
    *(float4*)(Y + idx) = o;
}

// ---------------------------------------------------------------------------
// Shared MFMA k-loop: 128x128 tile, BK=64, linear LDS [128][64] ushort with
// XOR swizzle (byte ^= (row&7)<<4), staged via global_load_lds width=16.
static __device__ __forceinline__ void gemm_kloop128(
    const ushort* __restrict__ A, const ushort* __restrict__ B, int K,
    int m0, int n0, int k_begin, int k_end,
    ushort* AsU, ushort* BsU, f32x4 acc[4][4], int tid) {
    char* As = (char*)AsU;
    char* Bs = (char*)BsU;
    int lane = tid & 63, w = tid >> 6;
    int g = lane >> 4, c = lane & 15;
    int wr = w >> 1, wc = w & 1;
    int srow[4], scol[4];
#pragma unroll
    for (int r = 0; r < 4; r++) {
        int p = r * 4096 + w * 1024 + lane * 16;
        int row = p >> 7;
        int bp = (p & 127) ^ ((row & 7) << 4);
        srow[r] = row;
        scol[r] = bp >> 1;
    }
    for (int k0 = k_begin; k0 < k_end; k0 += 64) {
        __syncthreads();
#pragma unroll
        for (int r = 0; r < 4; r++) {
            gload16(A + (size_t)(m0 + srow[r]) * K + k0 + scol[r],
                    As + r * 4096 + w * 1024);
            gload16(B + (size_t)(n0 + srow[r]) * K + k0 + scol[r],
                    Bs + r * 4096 + w * 1024);
        }
        __syncthreads();
#pragma unroll
        for (int kk = 0; kk < 2; kk++) {
            short8t af[4], bf[4];
#pragma unroll
            for (int i = 0; i < 4; i++) {
                int ra = wr * 64 + i * 16 + c;
                af[i] = *(const short8t*)(As + ra * 128 + ((kk * 64 + g * 16) ^ ((ra & 7) << 4)));
                int rb = wc * 64 + i * 16 + c;
                bf[i] = *(const short8t*)(Bs + rb * 128 + ((kk * 64 + g * 16) ^ ((rb & 7) << 4)));
            }
#pragma unroll
            for (int i = 0; i < 4; i++)
#pragma unroll
                for (int j = 0; j < 4; j++)
                    acc[i][j] = __builtin_amdgcn_mfma_f32_16x16x32_bf16(
                        af[i], bf[j], acc[i][j], 0, 0, 0);
        }
    }
}

// ---------------------------------------------------------------------------
// QKV gemm: [2048 x 4608] = XB @ WQKV^T + qkvbias, K=768; routed outputs.
__global__ __launch_bounds__(256) void gemm_qkv(
    const ushort* __restrict__ A, const ushort* __restrict__ Bw,
    const float* __restrict__ qkvbias,
    float* __restrict__ Q, float* __restrict__ Kf, float* __restrict__ Vf) {
    __shared__ __align__(16) ushort AsU[8192];
    __shared__ __align__(16) ushort BsU[8192];
    int tid = threadIdx.x;
    int lane = tid & 63, wid = tid >> 6;
    int wr = wid >> 1, wc = wid & 1;
    int g = lane >> 4, c = lane & 15;
    int m0 = blockIdx.x * 128, n0 = blockIdx.y * 128;
    f32x4 acc[4][4] = {};
    gemm_kloop128(A, Bw, 768, m0, n0, 0, 768, AsU, BsU, acc, tid);
    int y = blockIdx.y;
    float* outp; int nstr, nbase;
    if (y < 24)      { outp = Q;  nstr = 3072; nbase = 0; }
    else if (y < 30) { outp = Kf; nstr = 768;  nbase = 3072; }
    else             { outp = Vf; nstr = 768;  nbase = 3840; }
#pragma unroll
    for (int j = 0; j < 4; j++) {
        int n = n0 + wc * 64 + j * 16 + c;
        float bv = qkvbias[n];
#pragma unroll
        for (int i = 0; i < 4; i++) {
#pragma unroll
            for (int r = 0; r < 4; r++) {
                int m = m0 + wr * 64 + i * 16 + g * 4 + r;
                outp[(size_t)m * nstr + (n - nbase)] = acc[i][j][r] + bv;
            }
        }
    }
}

// ---------------------------------------------------------------------------
// Final gemm: Y += 0.25*(ctxb @ WoT^T), K=3072 split 3 ways. grid (16,6,3)
__global__ __launch_bounds__(256) void gemm_fin(
    const ushort* __restrict__ A, const ushort* __restrict__ Bw,
    float* __restrict__ Y) {
    __shared__ __align__(16) ushort AsU[8192];
    __shared__ __align__(16) ushort BsU[8192];
    int tid = threadIdx.x;
    int lane = tid & 63, wid = tid >> 6;
    int wr = wid >> 1, wc = wid & 1;
    int g = lane >> 4, c = lane & 15;
    int m0 = blockIdx.x * 128, n0 = blockIdx.y * 128;
    int kz = blockIdx.z * 1024;
    f32x4 acc[4][4] = {};
    gemm_kloop128(A, Bw, 3072, m0, n0, kz, kz + 1024, AsU, BsU, acc, tid);
#pragma unroll
    for (int j = 0; j < 4; j++) {
        int n = n0 + wc * 64 + j * 16 + c;
#pragma unroll
        for (int i = 0; i < 4; i++) {
#pragma unroll
            for (int r = 0; r < 4; r++) {
                int m = m0 + wr * 64 + i * 16 + g * 4 + r;
                atomicAdd(&Y[(size_t)m * 768 + n], 0.25f * acc[i][j][r]);
            }
        }
    }
}

// ---------------------------------------------------------------------------
// Rotate per-head 64-vectors, emit head-major bf16; optional rks = 0.125/|k|
__global__ void rot2_kernel(const float* __restrict__ in, int heads,
                            ushort* __restrict__ outb, float* __restrict__ rkso,
                            const float* __restrict__ ws) {
    int idx = blockIdx.x * 256 + threadIdx.x;
    if (idx >= MROWS * heads) return;
    int r = idx / heads;
    int hd = idx - r * heads;
    int tloc = r & (T_ - 1);
    int b = r >> 10;
    const float* p = in + (size_t)r * (heads * 64) + hd * 64;
    const float* b1 = ws + OFF_B1 + tloc * 32;
    const float* b2 = ws + OFF_B2 + tloc * 32;
    __align__(16) ushort ob[64];
    float nrm = 0.f;
#pragma unroll
    for (int i = 0; i < 8; i++) {
        float4 lo = *(const float4*)(p + i * 4);
        float4 hi = *(const float4*)(p + 32 + i * 4);
        float4 c1 = *(const float4*)(b1 + i * 4);
        float4 c2 = *(const float4*)(b2 + i * 4);
        float o1[4], o2[4];
        o1[0] = lo.x * c1.x - hi.x * c2.x;  o2[0] = lo.x * c2.x + hi.x * c1.x;
        o1[1] = lo.y * c1.y - hi.y * c2.y;  o2[1] = lo.y * c2.y + hi.y * c1.y;
        o1[2] = lo.z * c1.z - hi.z * c2.z;  o2[2] = lo.z * c2.z + hi.z * c1.z;
        o1[3] = lo.w * c1.w - hi.w * c2.w;  o2[3] = lo.w * c2.w + hi.w * c1.w;
#pragma unroll
        for (int j = 0; j < 4; j++) {
            ob[i * 4 + j]      = f2bf(o1[j]);
            ob[32 + i * 4 + j] = f2bf(o2[j]);
            nrm += o1[j] * o1[j] + o2[j] * o2[j];
        }
    }
    ushort* op = outb + ((size_t)(b * heads + hd) * T_ + tloc) * 64;
#pragma unroll
    for (int i = 0; i < 8; i++) *(int4*)(op + i * 8) = *(const int4*)&ob[i * 8];
    if (rkso) rkso[((b * heads + hd) << 10) + tloc] = ATTNSCALE_ / sqrtf(fmaxf(nrm, 1e-6f));
}

// ---------------------------------------------------------------------------
// V fp32 [2048][768] -> per-head TRANSPOSED bf16: VbT[(b*12+hk)][d][t]
// grid (16 t-tiles, 24 heads)
__global__ __launch_bounds__(256) void vconvT_kernel(const float* __restrict__ V,
                                                     ushort* __restrict__ VbT) {
    __shared__ float tile[64][65];
    int head = blockIdx.y;                 // b*12 + hk
    int b = head / NH, hk = head - b * NH;
    int t0 = blockIdx.x * 64;
    int tx = threadIdx.x & 63, ty = threadIdx.x >> 6;
#pragma unroll
    for (int p = 0; p < 16; p++) {
        int trow = p * 4 + ty;
        tile[trow][tx] = V[(size_t)(b * T_ + t0 + trow) * 768 + hk * 64 + tx];
    }
    __syncthreads();
#pragma unroll
    for (int p = 0; p < 16; p++) {
        int d = p * 4 + ty;
        VbT[(size_t)head * 65536 + (size_t)d * 1024 + t0 + tx] = f2bf(tile[tx][d]);
    }
}

// ---------------------------------------------------------------------------
// MFMA flash attention v5: v4 + double-buffered staging, ONE barrier/stage.
// Per stage: issue next-tile global_load_lds -> compute current -> barrier.
__global__ __launch_bounds__(512) void attn_mfma5(
    const ushort* __restrict__ Qb, const ushort* __restrict__ Kb,
    const ushort* __restrict__ VbT, const float* __restrict__ rks,
    const float* __restrict__ sinks, const float* __restrict__ vnull,
    ushort* __restrict__ ctxb) {
    __shared__ __align__(16) char KsB[2][8192];   // [64 s-rows][128 B] swizzled
    __shared__ __align__(16) char VtB[2][8192];   // [64 d-rows][128 B] swizzled
    __shared__ __align__(16) char PsB[8][2048];   // per wave [16 q-rows][128 B]
    __shared__ float rk_s[2][64];
    int tid  = threadIdx.x;
    int lane = tid & 63;
    int wid  = tid >> 6;               // 0..7
    int p  = 7 - blockIdx.x;           // deepest q-blocks first
    int bh = blockIdx.y;               // 0..95 = b*48 + h
    int b = bh / HT, h = bh - b * HT;
    int hk = h % NH;
    int qt0 = p * 128;
    int g = lane >> 4;
    int c = lane & 15;
    int rowbase = qt0 + wid * 16;      // wave's first global q-row

    const ushort* qrow = Qb + ((size_t)(b * HT + h) * T_ + rowbase + c) * 64;
    short8t qa0 = *(const short8t*)(qrow + g * 8);
    short8t qa1 = *(const short8t*)(qrow + 32 + g * 8);

    f32x4 oacc[4] = {};
    float sumw[4] = {0.f, 0.f, 0.f, 0.f};

    const size_t kvbase = (size_t)(b * NH + hk) * T_;
    const ushort* Kt0 = Kb + kvbase * 64;          // [t][64]
    const ushort* Vt0 = VbT + kvbase * 64;         // [d][1024] head base
    int drow  = tid >> 3;                          // dest row 0..63
    int sbyte = ((tid & 7) * 16) ^ ((drow & 7) << 4);
    int scolu = sbyte >> 1;                        // source col (ushorts)
    char* Ps = PsB[wid];

    int nt = 2 * p + 2;
    // prologue: stage tile 0 into buffer 0
    gload16(Kt0 + (size_t)drow * 64 + scolu, KsB[0] + wid * 1024);
    gload16(Vt0 + (size_t)drow * 1024 + scolu, VtB[0] + wid * 1024);
    if (tid < 64) rk_s[0][tid] = rks[kvbase + tid];
    __syncthreads();

    for (int st = 0; st < nt; st++) {
        int cur = st & 1;
        int s0 = st * 64;
        // issue next-tile loads into the other buffer (overlap with compute)
        if (st + 1 < nt) {
            int s1 = s0 + 64;
            gload16(Kt0 + (size_t)(s1 + drow) * 64 + scolu, KsB[cur ^ 1] + wid * 1024);
            gload16(Vt0 + (size_t)drow * 1024 + s1 + scolu, VtB[cur ^ 1] + wid * 1024);
            if (tid < 64) rk_s[cur ^ 1][tid] = rks[kvbase + (size_t)s1 + tid];
        }
        if (s0 <= rowbase + 15) {      // wave has unmasked rows in this tile
            bool diag = (s0 + 63 > rowbase);
            const char* Kc = KsB[cur];
            const char* Vc = VtB[cur];
            const float* rkc = rk_s[cur];

            // S = Q @ K^T
            f32x4 sfr[4];
#pragma unroll
            for (int f = 0; f < 4; f++) {
                int row = f * 16 + c, sw = (row & 7) << 4;
                f32x4 cacc = {0.f, 0.f, 0.f, 0.f};
                short8t kb0 = *(const short8t*)(Kc + row * 128 + ((g * 16) ^ sw));
                cacc = __builtin_amdgcn_mfma_f32_16x16x32_bf16(qa0, kb0, cacc, 0, 0, 0);
                short8t kb1 = *(const short8t*)(Kc + row * 128 + ((64 + g * 16) ^ sw));
                cacc = __builtin_amdgcn_mfma_f32_16x16x32_bf16(qa1, kb1, cacc, 0, 0, 0);
                sfr[f] = cacc;
            }
            // nonlinearity + mask + P -> LDS (swizzled)
#pragma unroll
            for (int f = 0; f < 4; f++) {
                int scol = f * 16 + c;
                float rkv = rkc[scol];
#pragma unroll
                for (int r = 0; r < 4; r++) {
                    int trow = g * 4 + r;
                    float x = sfr[f][r] * rkv;
                    float w = __logf(1.f + __expf(x));
                    w = w * __builtin_amdgcn_rcpf(1.f + __expf(-SCALE_W * w));
                    if (diag && s0 + scol > rowbase + trow) w = 0.f;
                    sumw[r] += w;
                    *(ushort*)(Ps + trow * 128 + ((scol * 2) ^ ((trow & 7) << 4))) = f2bf(w);
                }
            }
            // O += P @ V
#pragma unroll
            for (int hf = 0; hf < 2; hf++) {
                short8t pa = *(const short8t*)(Ps + c * 128 +
                                               ((hf * 64 + g * 16) ^ ((c & 7) << 4)));
#pragma unroll
                for (int f = 0; f < 4; f++) {
                    int row = f * 16 + c;
                    short8t vb = *(const short8t*)(Vc + row * 128 +
                                                   ((hf * 64 + g * 16) ^ ((row & 7) << 4)));
                    oacc[f] = __builtin_amdgcn_mfma_f32_16x16x32_bf16(pa, vb, oacc[f], 0, 0, 0);
                }
            }
        }
        __syncthreads();   // drains next-tile loads (covered by compute) + buffer swap
    }

#pragma unroll
    for (int m = 1; m < 16; m <<= 1) {
#pragma unroll
        for (int r = 0; r < 4; r++) sumw[r] += __shfl_xor(sumw[r], m, 64);
    }
    float skv = sinks[h];
    float alpha[4], ps[4];
#pragma unroll
    for (int r = 0; r < 4; r++) {
        alpha[r] = 1.0f / (sumw[r] + skv + 1e-6f);
        ps[r] = skv * alpha[r];
    }
    int nb = h / NH;
#pragma unroll
    for (int f = 0; f < 4; f++) {
        float vnv = vnull[h * 64 + f * 16 + c];
#pragma unroll
        for (int r = 0; r < 4; r++) {
            int t = rowbase + g * 4 + r;
            ctxb[(size_t)(b * T_ + t) * 3072 + nb * 768 + hk * 64 + f * 16 + c]
                = f2bf(oacc[f][r] * alpha[r] + ps[r] * vnv);
        }
    }
}

// ---------------------------------------------------------------------------
extern "C" void kernel_launch(void* const* d_in, const int* in_sizes, int n_in,
                              void* d_out, int out_size, void* d_ws, size_t ws_size,
                              hipStream_t stream) {
    const float* X   = (const float*)d_in[0];
    const float* Wq  = (const float*)d_in[1];
    const float* bq  = (const float*)d_in[2];
    const float* Wk  = (const float*)d_in[3];
    const float* bk  = (const float*)d_in[4];
    const float* Wv  = (const float*)d_in[5];
    const float* bv  = (const float*)d_in[6];
    const float* Aw  = (const float*)d_in[7];
    const float* idb = (const float*)d_in[8];
    const float* sk  = (const float*)d_in[9];
    const float* vn  = (const float*)d_in[10];
    const float* Wo  = (const float*)d_in[11];
    const float* bo  = (const float*)d_in[12];
    float* ws = (float*)d_ws;
    float* Y  = (float*)d_out;

    ushort* WQKV = (ushort*)(ws + OFF_WQKV);
    hipLaunchKernelGGL(cheb_kernel, dim3(4), dim3(256), 0, stream, ws);
    hipLaunchKernelGGL(prep_wq, dim3(48, 3), dim3(256), 0, stream, Aw, idb, Wq, bq, ws);
    hipLaunchKernelGGL(conv_bf16, dim3(576), dim3(256), 0, stream,
                       Wk, WQKV + (size_t)3072 * 768);
    hipLaunchKernelGGL(conv_bf16, dim3(576), dim3(256), 0, stream,
                       Wv, WQKV + (size_t)3840 * 768);
    hipLaunchKernelGGL(conv_bf16, dim3(1536), dim3(256), 0, stream,
                       X, (ushort*)(ws + OFF_XB));
    hipLaunchKernelGGL(woT_kernel, dim3(12, 12, 4), dim3(256), 0, stream,
                       Wo, (ushort*)(ws + OFF_WOT));
    hipLaunchKernelGGL(bias_prep, dim3(3), dim3(256), 0, stream, bo, bk, bv, ws);
    // combined QKV projection
    hipLaunchKernelGGL(gemm_qkv, dim3(16, 36), dim3(256), 0, stream,
                       (const ushort*)(ws + OFF_XB), WQKV, ws + OFF_QKVB,
                       ws + OFF_QF, ws + OFF_KF, ws + OFF_VF);
    hipLaunchKernelGGL(rot2_kernel, dim3(96), dim3(256), 0, stream,
                       ws + OFF_KF, NH, (ushort*)(ws + OFF_KB), ws + OFF_RKS, ws);
    // V -> per-head transposed bf16
    hipLaunchKernelGGL(vconvT_kernel, dim3(16, 24), dim3(256), 0, stream,
                       ws + OFF_VF, (ushort*)(ws + OFF_VB));
    hipLaunchKernelGGL(rot2_kernel, dim3(384), dim3(256), 0, stream,
                       ws + OFF_QF, HT, (ushort*)(ws + OFF_QB), (float*)nullptr, ws);
    // MFMA flash attention v5 (double-buffered, 1 barrier/stage)
    hipLaunchKernelGGL(attn_mfma5, dim3(8, 96), dim3(512), 0, stream,
                       (const ushort*)(ws + OFF_QB), (const ushort*)(ws + OFF_KB),
                       (const ushort*)(ws + OFF_VB), ws + OFF_RKS, sk, vn,
                       (ushort*)(ws + OFF_CTXB));
    // output projection: Y = bsum + 0.25 * ctxb @ WoT^T  (init + split-K atomic)
    hipLaunchKernelGGL(y_init, dim3(1536), dim3(256), 0, stream, ws + OFF_BSUM, Y);
    hipLaunchKernelGGL(gemm_fin, dim3(16, 6, 3), dim3(256), 0, stream,
                       (const ushort*)(ws + OFF_CTXB), (const ushort*)(ws + OFF_WOT), Y);
}

// Round 11
// 282.156 us; speedup vs baseline: 1.1345x; 1.1345x over previous
//
#include <hip/hip_runtime.h>
#include <math.h>

#define B_ 2
#define T_ 1024
#define C_ 768
#define NH 12
#define NBR 4
#define DH_ 64
#define HT 48
#define MROWS (B_*T_)   // 2048

#define SCALE_W 1.8137993642342178f   // pi/sqrt(3)
#define ATTNSCALE_ 0.125f             // 64^-0.5

// ---------------- workspace layout (float offsets, audited) ----------------
#define OFF_B1    0                          // fp32[1024*32]
#define OFF_B2    (OFF_B1 + 32768)           // 32768   fp32[1024*32]
#define OFF_QKVB  (OFF_B2 + 32768)           // 65536   fp32[4608]  (Ebq|bk|bv)
#define OFF_BSUM  (OFF_QKVB + 4608)          // 70144   fp32[768]
#define OFF_WQKV  (OFF_BSUM + 768)           // 70912   ushort[4608*768] -> 1769472 fl
#define OFF_XB    (OFF_WQKV + 1769472)       // 1840384 ushort[2048*768] -> 786432 fl
#define OFF_WOT   (OFF_XB + 786432)          // 2626816 ushort[768*3072] -> 1179648 fl
#define OFF_QF    (OFF_WOT + 1179648)        // 3806464 fp32[2048*3072] = 6291456 fl
#define OFF_KF    (OFF_QF + 6291456)         // 10097920 fp32[2048*768] = 1572864 fl
#define OFF_VF    (OFF_KF + 1572864)         // 11670784 fp32[2048*768]
// bf16 Q aliases dead fp32 KF+VF (needs 3145728 fl, KF+VF = 3145728 exactly)
#define OFF_QB    OFF_KF
#define OFF_KB    (OFF_VF + 1572864)         // 13243648 ushort[2*12*1024*64] -> 786432 fl
#define OFF_VB    (OFF_KB + 786432)          // 14030080 -> 786432 fl  (V^T head-major)
#define OFF_RKS   (OFF_VB + 786432)          // 14816512 fp32[24576]
// bf16 ctx aliases dead fp32 QF (needs 3145728 fl of 6291456)
#define OFF_CTXB  OFF_QF
// end = 14841088 floats = 59.4 MB

typedef __attribute__((ext_vector_type(8))) short short8t;
typedef __attribute__((ext_vector_type(4))) float f32x4;

__device__ inline ushort f2bf(float f) {
    union { float f; unsigned u; } v; v.f = f;
    unsigned r = (v.u + 0x7FFFu + ((v.u >> 16) & 1u)) >> 16;
    return (ushort)r;
}

typedef __attribute__((address_space(3))) void lds_vt;
typedef const __attribute__((address_space(1))) void gbl_vt;
static __device__ __forceinline__ void gload16(const void* g, void* l) {
    __builtin_amdgcn_global_load_lds((gbl_vt*)g, (lds_vt*)l, 16, 0, 0);
}

// ---------------------------------------------------------------------------
__global__ void cheb_kernel(float* __restrict__ ws) {
    int t = blockIdx.x * 256 + threadIdx.x;
    if (t >= T_) return;
    float* b1 = ws + OFF_B1 + t * 32;
    float* b2 = ws + OFF_B2 + t * 32;
    float x = 2.0f * (float)t / 1023.0f - 1.0f;
    float Tp = 1.0f, Tc = x;
    for (int j = 0; j < 32; j++) {
        float r1 = Tc;
        float r2 = 2.0f * x * Tc - Tp;
        float nr = sqrtf(r1 * r1 + r2 * r2 + 1e-8f);
        b1[j] = r1 / nr;
        b2[j] = r2 / nr;
        Tp = r2;
        Tc = 2.0f * x * r2 - r1;
    }
}

// ---------------------------------------------------------------------------
// Fold M_h into Wq -> bf16 rows [0,3072) of WQKV; Ebq -> QKVB[0..3072)
__global__ __launch_bounds__(256) void prep_wq(
    const float* __restrict__ Aw, const float* __restrict__ idb,
    const float* __restrict__ Wq, const float* __restrict__ bq,
    float* __restrict__ ws) {
    __shared__ float Ms[64][64];
    int h = blockIdx.x;
    int tid = threadIdx.x;
    for (int i = tid; i < 4096; i += 256) {
        int d = i >> 6, e = i & 63;
        float v = Aw[d * 64 + e] - Aw[e * 64 + d];
        if (d == e) v += 1.0f + idb[h * 64 + d];
        Ms[d][e] = v;
    }
    __syncthreads();
    int c = blockIdx.y * 256 + tid;
    float wq[64];
#pragma unroll
    for (int d = 0; d < 64; d++) wq[d] = Wq[(size_t)(h * 64 + d) * 768 + c];
    ushort* EWqb = (ushort*)(ws + OFF_WQKV);
    for (int e = 0; e < 64; e++) {
        float acc = 0.f;
#pragma unroll
        for (int d = 0; d < 64; d++) acc += Ms[d][e] * wq[d];
        EWqb[(size_t)(h * 64 + e) * 768 + c] = f2bf(acc);
    }
    if (blockIdx.y == 0 && tid < 64) {
        int e = tid;
        float acc = 0.f;
        for (int d = 0; d < 64; d++) acc += Ms[d][e] * bq[h * 64 + d];
        ws[OFF_QKVB + h * 64 + e] = acc;
    }
}

// ---------------------------------------------------------------------------
__global__ void conv_bf16(const float* __restrict__ src, ushort* __restrict__ dst) {
    int i = (blockIdx.x * 256 + threadIdx.x) * 4;
    float4 v = *(const float4*)(src + i);
    ushort4 o;
    o.x = f2bf(v.x); o.y = f2bf(v.y); o.z = f2bf(v.z); o.w = f2bf(v.w);
    *(ushort4*)(dst + i) = o;
}

// ---------------------------------------------------------------------------
// WoT[c][nb*768+k] = bf16(Wo[nb][k][c])   grid (12,12,4)
__global__ __launch_bounds__(256) void woT_kernel(const float* __restrict__ Wo,
                                                  ushort* __restrict__ WoT) {
    __shared__ float tile[64][65];
    int nb = blockIdx.z;
    int k0 = blockIdx.x * 64, c0 = blockIdx.y * 64;
    int tx = threadIdx.x & 63, ty = threadIdx.x >> 6;
#pragma unroll
    for (int p = 0; p < 16; p++) {
        int ky = p * 4 + ty;
        tile[ky][tx] = Wo[((size_t)nb * 768 + k0 + ky) * 768 + c0 + tx];
    }
    __syncthreads();
#pragma unroll
    for (int p = 0; p < 16; p++) {
        int cy = p * 4 + ty;
        WoT[(size_t)(c0 + cy) * 3072 + nb * 768 + k0 + tx] = f2bf(tile[tx][cy]);
    }
}

// bsum + pack bk,bv into QKVB tail
__global__ void bias_prep(const float* __restrict__ bo, const float* __restrict__ bk,
                          const float* __restrict__ bv, float* __restrict__ ws) {
    int n = blockIdx.x * 256 + threadIdx.x;
    if (n < 768) {
        ws[OFF_BSUM + n] = 0.25f * (bo[n] + bo[768 + n] + bo[1536 + n] + bo[2304 + n]);
        ws[OFF_QKVB + 3072 + n] = bk[n];
        ws[OFF_QKVB + 3840 + n] = bv[n];
    }
}

// Y pre-init with branch-mean bias (gemm_fin accumulates atomically on top)
__global__ void y_init(const float* __restrict__ bsum, float* __restrict__ Y) {
    int idx = (blockIdx.x * 256 + threadIdx.x) * 4;
    int n = idx - (idx / 768) * 768;
    float4 o = { bsum[n], bsum[n + 1], bsum[n + 2], bsum[n + 3] };
    *(float4*)(Y + idx) = o;
}

// ---------------------------------------------------------------------------
// MFMA k-loop, 64x128 tile (BM=64, BN=128), BK=64. Linear LDS + XOR swizzle
// (byte ^= (row&7)<<4), staged via global_load_lds width=16. 4 waves (2x2),
// each wave computes 32x64 via 2x4 16x16x32 fragments.
static __device__ __forceinline__ void gemm_kloop64(
    const ushort* __restrict__ A, const ushort* __restrict__ B, int K,
    int m0, int n0, int k_begin, int k_end,
    char* As /*8KB*/, char* Bs /*16KB*/, f32x4 acc[2][4], int tid) {
    int lane = tid & 63, w = tid >> 6;
    int g = lane >> 4, c = lane & 15;
    int wr = w >> 1, wc = w & 1;
    // staging coords: dest p -> (row, inverse-swizzled col)
    int sArow[2], sAcol[2];
#pragma unroll
    for (int r = 0; r < 2; r++) {
        int p = r * 4096 + tid * 16;
        int row = p >> 7;
        int bp = (p & 127) ^ ((row & 7) << 4);
        sArow[r] = row; sAcol[r] = bp >> 1;
    }
    int sBrow[4], sBcol[4];
#pragma unroll
    for (int r = 0; r < 4; r++) {
        int p = r * 4096 + tid * 16;
        int row = p >> 7;
        int bp = (p & 127) ^ ((row & 7) << 4);
        sBrow[r] = row; sBcol[r] = bp >> 1;
    }
    for (int k0 = k_begin; k0 < k_end; k0 += 64) {
        __syncthreads();
#pragma unroll
        for (int r = 0; r < 2; r++)
            gload16(A + (size_t)(m0 + sArow[r]) * K + k0 + sAcol[r],
                    As + r * 4096 + w * 1024);
#pragma unroll
        for (int r = 0; r < 4; r++)
            gload16(B + (size_t)(n0 + sBrow[r]) * K + k0 + sBcol[r],
                    Bs + r * 4096 + w * 1024);
        __syncthreads();
#pragma unroll
        for (int kk = 0; kk < 2; kk++) {
            short8t af[2], bf[4];
#pragma unroll
            for (int i = 0; i < 2; i++) {
                int ra = wr * 32 + i * 16 + c;
                af[i] = *(const short8t*)(As + ra * 128 + ((kk * 64 + g * 16) ^ ((ra & 7) << 4)));
            }
#pragma unroll
            for (int j = 0; j < 4; j++) {
                int rb = wc * 64 + j * 16 + c;
                bf[j] = *(const short8t*)(Bs + rb * 128 + ((kk * 64 + g * 16) ^ ((rb & 7) << 4)));
            }
#pragma unroll
            for (int i = 0; i < 2; i++)
#pragma unroll
                for (int j = 0; j < 4; j++)
                    acc[i][j] = __builtin_amdgcn_mfma_f32_16x16x32_bf16(
                        af[i], bf[j], acc[i][j], 0, 0, 0);
        }
    }
}

// ---------------------------------------------------------------------------
// QKV gemm: [2048 x 4608] = XB @ WQKV^T + qkvbias, K=768. grid (32,36)
__global__ __launch_bounds__(256) void gemm_qkv(
    const ushort* __restrict__ A, const ushort* __restrict__ Bw,
    const float* __restrict__ qkvbias,
    float* __restrict__ Q, float* __restrict__ Kf, float* __restrict__ Vf) {
    __shared__ __align__(16) char As[8192];
    __shared__ __align__(16) char Bs[16384];
    int tid = threadIdx.x;
    int lane = tid & 63, wid = tid >> 6;
    int wr = wid >> 1, wc = wid & 1;
    int g = lane >> 4, c = lane & 15;
    int m0 = blockIdx.x * 64, n0 = blockIdx.y * 128;
    f32x4 acc[2][4] = {};
    gemm_kloop64(A, Bw, 768, m0, n0, 0, 768, As, Bs, acc, tid);
    int y = blockIdx.y;
    float* outp; int nstr, nbase;
    if (y < 24)      { outp = Q;  nstr = 3072; nbase = 0; }
    else if (y < 30) { outp = Kf; nstr = 768;  nbase = 3072; }
    else             { outp = Vf; nstr = 768;  nbase = 3840; }
#pragma unroll
    for (int j = 0; j < 4; j++) {
        int n = n0 + wc * 64 + j * 16 + c;
        float bv = qkvbias[n];
#pragma unroll
        for (int i = 0; i < 2; i++) {
#pragma unroll
            for (int r = 0; r < 4; r++) {
                int m = m0 + wr * 32 + i * 16 + g * 4 + r;
                outp[(size_t)m * nstr + (n - nbase)] = acc[i][j][r] + bv;
            }
        }
    }
}

// ---------------------------------------------------------------------------
// Final gemm: Y += 0.25*(ctxb @ WoT^T), K=3072 split 3 ways. grid (32,6,3)
__global__ __launch_bounds__(256) void gemm_fin(
    const ushort* __restrict__ A, const ushort* __restrict__ Bw,
    float* __restrict__ Y) {
    __shared__ __align__(16) char As[8192];
    __shared__ __align__(16) char Bs[16384];
    int tid = threadIdx.x;
    int lane = tid & 63, wid = tid >> 6;
    int wr = wid >> 1, wc = wid & 1;
    int g = lane >> 4, c = lane & 15;
    int m0 = blockIdx.x * 64, n0 = blockIdx.y * 128;
    int kz = blockIdx.z * 1024;
    f32x4 acc[2][4] = {};
    gemm_kloop64(A, Bw, 3072, m0, n0, kz, kz + 1024, As, Bs, acc, tid);
#pragma unroll
    for (int j = 0; j < 4; j++) {
        int n = n0 + wc * 64 + j * 16 + c;
#pragma unroll
        for (int i = 0; i < 2; i++) {
#pragma unroll
            for (int r = 0; r < 4; r++) {
                int m = m0 + wr * 32 + i * 16 + g * 4 + r;
                atomicAdd(&Y[(size_t)m * 768 + n], 0.25f * acc[i][j][r]);
            }
        }
    }
}

// ---------------------------------------------------------------------------
// Rotate per-head 64-vectors, emit head-major bf16; optional rks = 0.125/|k|
__global__ void rot2_kernel(const float* __restrict__ in, int heads,
                            ushort* __restrict__ outb, float* __restrict__ rkso,
                            const float* __restrict__ ws) {
    int idx = blockIdx.x * 256 + threadIdx.x;
    if (idx >= MROWS * heads) return;
    int r = idx / heads;
    int hd = idx - r * heads;
    int tloc = r & (T_ - 1);
    int b = r >> 10;
    const float* p = in + (size_t)r * (heads * 64) + hd * 64;
    const float* b1 = ws + OFF_B1 + tloc * 32;
    const float* b2 = ws + OFF_B2 + tloc * 32;
    __align__(16) ushort ob[64];
    float nrm = 0.f;
#pragma unroll
    for (int i = 0; i < 8; i++) {
        float4 lo = *(const float4*)(p + i * 4);
        float4 hi = *(const float4*)(p + 32 + i * 4);
        float4 c1 = *(const float4*)(b1 + i * 4);
        float4 c2 = *(const float4*)(b2 + i * 4);
        float o1[4], o2[4];
        o1[0] = lo.x * c1.x - hi.x * c2.x;  o2[0] = lo.x * c2.x + hi.x * c1.x;
        o1[1] = lo.y * c1.y - hi.y * c2.y;  o2[1] = lo.y * c2.y + hi.y * c1.y;
        o1[2] = lo.z * c1.z - hi.z * c2.z;  o2[2] = lo.z * c2.z + hi.z * c1.z;
        o1[3] = lo.w * c1.w - hi.w * c2.w;  o2[3] = lo.w * c2.w + hi.w * c1.w;
#pragma unroll
        for (int j = 0; j < 4; j++) {
            ob[i * 4 + j]      = f2bf(o1[j]);
            ob[32 + i * 4 + j] = f2bf(o2[j]);
            nrm += o1[j] * o1[j] + o2[j] * o2[j];
        }
    }
    ushort* op = outb + ((size_t)(b * heads + hd) * T_ + tloc) * 64;
#pragma unroll
    for (int i = 0; i < 8; i++) *(int4*)(op + i * 8) = *(const int4*)&ob[i * 8];
    if (rkso) rkso[((b * heads + hd) << 10) + tloc] = ATTNSCALE_ / sqrtf(fmaxf(nrm, 1e-6f));
}

// ---------------------------------------------------------------------------
// V fp32 [2048][768] -> per-head TRANSPOSED bf16: VbT[(b*12+hk)][d][t]
// grid (16 t-tiles, 24 heads)
__global__ __launch_bounds__(256) void vconvT_kernel(const float* __restrict__ V,
                                                     ushort* __restrict__ VbT) {
    __shared__ float tile[64][65];
    int head = blockIdx.y;                 // b*12 + hk
    int b = head / NH, hk = head - b * NH;
    int t0 = blockIdx.x * 64;
    int tx = threadIdx.x & 63, ty = threadIdx.x >> 6;
#pragma unroll
    for (int p = 0; p < 16; p++) {
        int trow = p * 4 + ty;
        tile[trow][tx] = V[(size_t)(b * T_ + t0 + trow) * 768 + hk * 64 + tx];
    }
    __syncthreads();
#pragma unroll
    for (int p = 0; p < 16; p++) {
        int d = p * 4 + ty;
        VbT[(size_t)head * 65536 + (size_t)d * 1024 + t0 + tx] = f2bf(tile[tx][d]);
    }
}

// ---------------------------------------------------------------------------
// MFMA flash attention v6: v5 + depth-balancing swizzle. Co-resident blocks
// (dispatch indices differing by 256 -> y>>5 in {0,1,2}) get depths
// {x, x+3, x+6} mod 8 so per-CU work is ~balanced (34 vs 48 units worst-case).
__global__ __launch_bounds__(512) void attn_mfma6(
    const ushort* __restrict__ Qb, const ushort* __restrict__ Kb,
    const ushort* __restrict__ VbT, const float* __restrict__ rks,
    const float* __restrict__ sinks, const float* __restrict__ vnull,
    ushort* __restrict__ ctxb) {
    __shared__ __align__(16) char KsB[2][8192];   // [64 s-rows][128 B] swizzled
    __shared__ __align__(16) char VtB[2][8192];   // [64 d-rows][128 B] swizzled
    __shared__ __align__(16) char PsB[8][2048];   // per wave [16 q-rows][128 B]
    __shared__ float rk_s[2][64];
    int tid  = threadIdx.x;
    int lane = tid & 63;
    int wid  = tid >> 6;               // 0..7
    int p  = (blockIdx.x + 3 * (blockIdx.y >> 5)) & 7;   // depth-balance swizzle
    int bh = blockIdx.y;               // 0..95 = b*48 + h
    int b = bh / HT, h = bh - b * HT;
    int hk = h % NH;
    int qt0 = p * 128;
    int g = lane >> 4;
    int c = lane & 15;
    int rowbase = qt0 + wid * 16;      // wave's first global q-row

    const ushort* qrow = Qb + ((size_t)(b * HT + h) * T_ + rowbase + c) * 64;
    short8t qa0 = *(const short8t*)(qrow + g * 8);
    short8t qa1 = *(const short8t*)(qrow + 32 + g * 8);

    f32x4 oacc[4] = {};
    float sumw[4] = {0.f, 0.f, 0.f, 0.f};

    const size_t kvbase = (size_t)(b * NH + hk) * T_;
    const ushort* Kt0 = Kb + kvbase * 64;          // [t][64]
    const ushort* Vt0 = VbT + kvbase * 64;         // [d][1024] head base
    int drow  = tid >> 3;                          // dest row 0..63
    int sbyte = ((tid & 7) * 16) ^ ((drow & 7) << 4);
    int scolu = sbyte >> 1;                        // source col (ushorts)
    char* Ps = PsB[wid];

    int nt = 2 * p + 2;
    // prologue: stage tile 0 into buffer 0
    gload16(Kt0 + (size_t)drow * 64 + scolu, KsB[0] + wid * 1024);
    gload16(Vt0 + (size_t)drow * 1024 + scolu, VtB[0] + wid * 1024);
    if (tid < 64) rk_s[0][tid] = rks[kvbase + tid];
    __syncthreads();

    for (int st = 0; st < nt; st++) {
        int cur = st & 1;
        int s0 = st * 64;
        // issue next-tile loads into the other buffer (overlap with compute)
        if (st + 1 < nt) {
            int s1 = s0 + 64;
            gload16(Kt0 + (size_t)(s1 + drow) * 64 + scolu, KsB[cur ^ 1] + wid * 1024);
            gload16(Vt0 + (size_t)drow * 1024 + s1 + scolu, VtB[cur ^ 1] + wid * 1024);
            if (tid < 64) rk_s[cur ^ 1][tid] = rks[kvbase + (size_t)s1 + tid];
        }
        if (s0 <= rowbase + 15) {      // wave has unmasked rows in this tile
            bool diag = (s0 + 63 > rowbase);
            const char* Kc = KsB[cur];
            const char* Vc = VtB[cur];
            const float* rkc = rk_s[cur];

            // S = Q @ K^T
            f32x4 sfr[4];
#pragma unroll
            for (int f = 0; f < 4; f++) {
                int row = f * 16 + c, sw = (row & 7) << 4;
                f32x4 cacc = {0.f, 0.f, 0.f, 0.f};
                short8t kb0 = *(const short8t*)(Kc + row * 128 + ((g * 16) ^ sw));
                cacc = __builtin_amdgcn_mfma_f32_16x16x32_bf16(qa0, kb0, cacc, 0, 0, 0);
                short8t kb1 = *(const short8t*)(Kc + row * 128 + ((64 + g * 16) ^ sw));
                cacc = __builtin_amdgcn_mfma_f32_16x16x32_bf16(qa1, kb1, cacc, 0, 0, 0);
                sfr[f] = cacc;
            }
            // nonlinearity + mask + P -> LDS (swizzled)
#pragma unroll
            for (int f = 0; f < 4; f++) {
                int scol = f * 16 + c;
                float rkv = rkc[scol];
#pragma unroll
                for (int r = 0; r < 4; r++) {
                    int trow = g * 4 + r;
                    float x = sfr[f][r] * rkv;
                    float w = __logf(1.f + __expf(x));
                    w = w * __builtin_amdgcn_rcpf(1.f + __expf(-SCALE_W * w));
                    if (diag && s0 + scol > rowbase + trow) w = 0.f;
                    sumw[r] += w;
                    *(ushort*)(Ps + trow * 128 + ((scol * 2) ^ ((trow & 7) << 4))) = f2bf(w);
                }
            }
            // O += P @ V
#pragma unroll
            for (int hf = 0; hf < 2; hf++) {
                short8t pa = *(const short8t*)(Ps + c * 128 +
                                               ((hf * 64 + g * 16) ^ ((c & 7) << 4)));
#pragma unroll
                for (int f = 0; f < 4; f++) {
                    int row = f * 16 + c;
                    short8t vb = *(const short8t*)(Vc + row * 128 +
                                                   ((hf * 64 + g * 16) ^ ((row & 7) << 4)));
                    oacc[f] = __builtin_amdgcn_mfma_f32_16x16x32_bf16(pa, vb, oacc[f], 0, 0, 0);
                }
            }
        }
        __syncthreads();   // drains next-tile loads (covered by compute) + buffer swap
    }

#pragma unroll
    for (int m = 1; m < 16; m <<= 1) {
#pragma unroll
        for (int r = 0; r < 4; r++) sumw[r] += __shfl_xor(sumw[r], m, 64);
    }
    float skv = sinks[h];
    float alpha[4], ps[4];
#pragma unroll
    for (int r = 0; r < 4; r++) {
        alpha[r] = 1.0f / (sumw[r] + skv + 1e-6f);
        ps[r] = skv * alpha[r];
    }
    int nb = h / NH;
#pragma unroll
    for (int f = 0; f < 4; f++) {
        float vnv = vnull[h * 64 + f * 16 + c];
#pragma unroll
        for (int r = 0; r < 4; r++) {
            int t = rowbase + g * 4 + r;
            ctxb[(size_t)(b * T_ + t) * 3072 + nb * 768 + hk * 64 + f * 16 + c]
                = f2bf(oacc[f][r] * alpha[r] + ps[r] * vnv);
        }
    }
}

// ---------------------------------------------------------------------------
extern "C" void kernel_launch(void* const* d_in, const int* in_sizes, int n_in,
                              void* d_out, int out_size, void* d_ws, size_t ws_size,
                              hipStream_t stream) {
    const float* X   = (const float*)d_in[0];
    const float* Wq  = (const float*)d_in[1];
    const float* bq  = (const float*)d_in[2];
    const float* Wk  = (const float*)d_in[3];
    const float* bk  = (const float*)d_in[4];
    const float* Wv  = (const float*)d_in[5];
    const float* bv  = (const float*)d_in[6];
    const float* Aw  = (const float*)d_in[7];
    const float* idb = (const float*)d_in[8];
    const float* sk  = (const float*)d_in[9];
    const float* vn  = (const float*)d_in[10];
    const float* Wo  = (const float*)d_in[11];
    const float* bo  = (const float*)d_in[12];
    float* ws = (float*)d_ws;
    float* Y  = (float*)d_out;

    ushort* WQKV = (ushort*)(ws + OFF_WQKV);
    hipLaunchKernelGGL(cheb_kernel, dim3(4), dim3(256), 0, stream, ws);
    hipLaunchKernelGGL(prep_wq, dim3(48, 3), dim3(256), 0, stream, Aw, idb, Wq, bq, ws);
    hipLaunchKernelGGL(conv_bf16, dim3(576), dim3(256), 0, stream,
                       Wk, WQKV + (size_t)3072 * 768);
    hipLaunchKernelGGL(conv_bf16, dim3(576), dim3(256), 0, stream,
                       Wv, WQKV + (size_t)3840 * 768);
    hipLaunchKernelGGL(conv_bf16, dim3(1536), dim3(256), 0, stream,
                       X, (ushort*)(ws + OFF_XB));
    hipLaunchKernelGGL(woT_kernel, dim3(12, 12, 4), dim3(256), 0, stream,
                       Wo, (ushort*)(ws + OFF_WOT));
    hipLaunchKernelGGL(bias_prep, dim3(3), dim3(256), 0, stream, bo, bk, bv, ws);
    // combined QKV projection (64x128 tiles, 1152 blocks)
    hipLaunchKernelGGL(gemm_qkv, dim3(32, 36), dim3(256), 0, stream,
                       (const ushort*)(ws + OFF_XB), WQKV, ws + OFF_QKVB,
                       ws + OFF_QF, ws + OFF_KF, ws + OFF_VF);
    hipLaunchKernelGGL(rot2_kernel, dim3(96), dim3(256), 0, stream,
                       ws + OFF_KF, NH, (ushort*)(ws + OFF_KB), ws + OFF_RKS, ws);
    // V -> per-head transposed bf16
    hipLaunchKernelGGL(vconvT_kernel, dim3(16, 24), dim3(256), 0, stream,
                       ws + OFF_VF, (ushort*)(ws + OFF_VB));
    hipLaunchKernelGGL(rot2_kernel, dim3(384), dim3(256), 0, stream,
                       ws + OFF_QF, HT, (ushort*)(ws + OFF_QB), (float*)nullptr, ws);
    // MFMA flash attention v6 (depth-balanced)
    hipLaunchKernelGGL(attn_mfma6, dim3(8, 96), dim3(512), 0, stream,
                       (const ushort*)(ws + OFF_QB), (const ushort*)(ws + OFF_KB),
                       (const ushort*)(ws + OFF_VB), ws + OFF_RKS, sk, vn,
                       (ushort*)(ws + OFF_CTXB));
    // output projection: Y = bsum + 0.25 * ctxb @ WoT^T  (init + split-K atomic)
    hipLaunchKernelGGL(y_init, dim3(1536), dim3(256), 0, stream, ws + OFF_BSUM, Y);
    hipLaunchKernelGGL(gemm_fin, dim3(32, 6, 3), dim3(256), 0, stream,
                       (const ushort*)(ws + OFF_CTXB), (const ushort*)(ws + OFF_WOT), Y);
}